// Round 12
// baseline (13731.747 us; speedup 1.0000x reference)
//
#include <hip/hip_runtime.h>
#include <cfloat>
#include <climits>

#define NEG 0.2f
#define GEPS 1e-5f
#define D 6
#define H 13   // 2*D+1
#define KOUT 16

#define GMAX 36
#define MAXC 46656      // GMAX^3
#define MAXPC 16        // atom slots per cell (rest -> spill list)
#define CS_TGT 2.2f     // target cell size
#define WPB 4           // waves (queries) per block
#define MARGIN 0.05f    // e-space margin (fallback path, proven in R9)

__device__ __forceinline__ float lrelu(float x){ return x >= 0.f ? x : NEG*x; }

// order-preserving float<->uint for atomic min/max
__device__ __forceinline__ unsigned fkey(float f){
  unsigned u = __float_as_uint(f);
  return (u & 0x80000000u) ? ~u : (u | 0x80000000u);
}
__device__ __forceinline__ float funkey(unsigned u){
  return __uint_as_float((u & 0x80000000u) ? (u ^ 0x80000000u) : ~u);
}

struct GridP {
  float bx,by,bz, csx,csy,csz, ivx,ivy,ivz;
  int gx,gy,gz;
};
// identical fp path in every kernel -> identical grid params
__device__ __forceinline__ GridP load_grid(const unsigned* bb){
  GridP g;
  g.bx = funkey(bb[0]); g.by = funkey(bb[1]); g.bz = funkey(bb[2]);
  float sx = fmaxf(funkey(bb[3]) - g.bx, 1e-5f);
  float sy = fmaxf(funkey(bb[4]) - g.by, 1e-5f);
  float sz = fmaxf(funkey(bb[5]) - g.bz, 1e-5f);
  int gx = (int)(sx/CS_TGT) + 1; gx = gx < 1 ? 1 : (gx > GMAX ? GMAX : gx);
  int gy = (int)(sy/CS_TGT) + 1; gy = gy < 1 ? 1 : (gy > GMAX ? GMAX : gy);
  int gz = (int)(sz/CS_TGT) + 1; gz = gz < 1 ? 1 : (gz > GMAX ? GMAX : gz);
  g.gx = gx; g.gy = gy; g.gz = gz;
  g.csx = sx/gx; g.csy = sy/gy; g.csz = sz/gz;
  g.ivx = gx/sx; g.ivy = gy/sy; g.ivz = gz/sz;
  return g;
}
__device__ __forceinline__ int cell1(float x, float b, float iv, int gdim){
  int c = (int)((x - b)*iv);
  return c < 0 ? 0 : (c >= gdim ? gdim-1 : c);
}

// ---------------- build kernels ----------------
__global__ void init_kernel(unsigned* bb, unsigned* fill, unsigned* spillCnt){
  int i = blockIdx.x*blockDim.x + threadIdx.x;
  if (i < MAXC) fill[i] = 0;
  if (i == 0){
    bb[0]=bb[1]=bb[2]=0xFFFFFFFFu;
    bb[3]=bb[4]=bb[5]=0u;
    spillCnt[0]=0;
  }
}

__global__ void bbox_kernel(const float* __restrict__ xyz, int n, unsigned* bb){
  int i = blockIdx.x*blockDim.x + threadIdx.x;
  if (i >= n) return;
  float x = xyz[3*i], y = xyz[3*i+1], z = xyz[3*i+2];
  atomicMin(&bb[0], fkey(x)); atomicMin(&bb[1], fkey(y)); atomicMin(&bb[2], fkey(z));
  atomicMax(&bb[3], fkey(x)); atomicMax(&bb[4], fkey(y)); atomicMax(&bb[5], fkey(z));
}

__global__ void scatter_kernel(const float* __restrict__ xyz, int n,
                               const unsigned* __restrict__ bb,
                               unsigned* fill, ushort* cellIdx,
                               ushort* spill, unsigned* spillCnt){
  int i = blockIdx.x*blockDim.x + threadIdx.x;
  if (i >= n) return;
  GridP g = load_grid(bb);
  float x = xyz[3*i], y = xyz[3*i+1], z = xyz[3*i+2];
  int cx = cell1(x, g.bx, g.ivx, g.gx);
  int cy = cell1(y, g.by, g.ivy, g.gy);
  int cz = cell1(z, g.bz, g.ivz, g.gz);
  int cid = (cz*g.gy + cy)*g.gx + cx;
  unsigned pos = atomicAdd(&fill[cid], 1u);
  if (pos < MAXPC) cellIdx[cid*MAXPC + pos] = (ushort)i;
  else {
    unsigned sp = atomicAdd(spillCnt, 1u);
    spill[sp] = (ushort)i;
  }
}

// xyz (n,3) -> float4 {x,y,z,|p|^2} (contract-off to match reference)
__global__ void pack_kernel(const float* __restrict__ xyz, float4* __restrict__ out, int n){
  int i = blockIdx.x*blockDim.x + threadIdx.x;
  if (i >= n) return;
  float x = xyz[3*i], y = xyz[3*i+1], z = xyz[3*i+2];
  float sq;
  {
#pragma clang fp contract(off)
    sq = (x*x + y*y) + z*z;
  }
  out[i] = make_float4(x,y,z,sq);
}

// atomtypes (n,6) -> 2-layer MLP -> out (n,6)
__global__ void tt_kernel(const float* __restrict__ at_in,
                          const float* __restrict__ w1, const float* __restrict__ b1,
                          const float* __restrict__ w2, const float* __restrict__ b2,
                          float* __restrict__ out, int n){
  int i = blockIdx.x*blockDim.x + threadIdx.x;
  if (i >= n) return;
  float x[D], h[D];
  #pragma unroll
  for (int j=0;j<D;j++) x[j] = at_in[i*D+j];
  #pragma unroll
  for (int o=0;o<D;o++){
    float acc = b1[o];
    #pragma unroll
    for (int j=0;j<D;j++) acc += w1[o*D+j]*x[j];
    h[o] = lrelu(acc);
  }
  #pragma unroll
  for (int o=0;o<D;o++){
    float acc = b2[o];
    #pragma unroll
    for (int j=0;j<D;j++) acc += w2[o*D+j]*h[j];
    out[i*D+o] = acc;
  }
}

// ascending value bitonic sort across 64 lanes
__device__ __forceinline__ void sort64f1(float& a, int lane){
  #pragma unroll
  for (int k=2;k<=64;k<<=1){
    #pragma unroll
    for (int j=k>>1;j>=1;j>>=1){
      float o = __shfl_xor(a, j);
      bool dir = ((lane&j)==0)==((lane&k)==0);
      a = dir ? fminf(a,o) : fmaxf(a,o);
    }
  }
}

// ascending lexicographic (d, i) bitonic sort across 64 lanes
__device__ __forceinline__ void sort64pair(float& d, int& i, int lane){
  #pragma unroll
  for (int k = 2; k <= 64; k <<= 1){
    #pragma unroll
    for (int j = k >> 1; j >= 1; j >>= 1){
      float od = __shfl_xor(d, j);
      int   oi = __shfl_xor(i, j);
      bool lower = (lane & j) == 0;
      bool asc   = (lane & k) == 0;
      bool oless = (od < d) || (od == d && oi < i);
      bool take  = (lower == asc) ? oless : !oless;
      d = take ? od : d;
      i = take ? oi : i;
    }
  }
}

// ascending lexicographic insert of (d,i) into sorted (td,ti)[K]
template<int K>
__device__ __forceinline__ void lex_insert(float (&td)[K], int (&ti)[K], float d, int i){
  float cd = d; int ci = i;
  #pragma unroll
  for (int t=0;t<K;++t){
    bool less = (cd < td[t]) || (cd == td[t] && ci < ti[t]);
    float nd = less ? cd : td[t]; int ni = less ? ci : ti[t];
    cd = less ? td[t] : cd;       ci = less ? ti[t] : ci;
    td[t] = nd; ti[t] = ni;
  }
}

// Grid KNN v2: one wave per query; expanding Chebyshev shells; per-lane
// REGISTER lex top-4 of exact contract-off (d2,idx); atoms (not cells) are
// lane-balanced: cb = lane>>4 stride 4, slot = lane&15 (one cell's atoms
// spread across 16 lanes). u = KSEL-th smallest of lane minima (>=KSEL
// distinct witnesses -> upper bound on true KSEL-th). Pruning/stop identical
// to R11 (proven). Validity: lane's 4th-stored <= u => possible hidden 5th
// => wave-parallel exact fallback (R9 logic). Exactness is unconditional.
template<int KSEL, int OUT_OFF>
__global__ __launch_bounds__(256)
void knn_grid2_kernel(const float4* __restrict__ candP, int ncand,
                      const float4* __restrict__ qarr, int nq,
                      const unsigned* __restrict__ bb,
                      const unsigned* __restrict__ fill,
                      const ushort* __restrict__ cellIdx,
                      const ushort* __restrict__ spill,
                      const unsigned* __restrict__ spillCnt,
                      int* __restrict__ oidx, float* __restrict__ odist){
  __shared__ float sdd[WPB][64];
  __shared__ int   sii[WPB][64];

  const int w = threadIdx.x >> 6;
  const int lane = threadIdx.x & 63;
  const int q = blockIdx.x*WPB + w;
  if (q >= nq) return;                     // wave-uniform; no barriers used

  const GridP g = load_grid(bb);
  const float4 qv = qarr[q];
  const int c0x = cell1(qv.x, g.bx, g.ivx, g.gx);
  const int c0y = cell1(qv.y, g.by, g.ivy, g.gy);
  const int c0z = cell1(qv.z, g.bz, g.ivz, g.gz);

  float td[4]; int ti[4];
  #pragma unroll
  for (int t=0;t<4;++t){ td[t]=FLT_MAX; ti[t]=INT_MAX; }
  float u = FLT_MAX; bool hasu = false;
  const int spc = (int)spillCnt[0];
  const int slotm = lane & 15;

  for (int s = 0; s <= GMAX; ++s){
    if (s == 0 && spc > 0){                // cell-overflow spill (usually 0)
      for (int t = lane; t < spc; t += 64){
        int gi = (int)spill[t];
        float4 cp = candP[gi];
        float d2;
        {
#pragma clang fp contract(off)
          float dot = qv.x*cp.x + qv.y*cp.y + qv.z*cp.z;
          d2 = (qv.w + cp.w) - 2.0f*dot;
        }
        if (d2 < td[3] || (d2 == td[3] && gi < ti[3])) lex_insert<4>(td, ti, d2, gi);
      }
    }
    const int B = 2*s+1, B2 = B*B, nbox = B2*B;
    const float rB2 = 1.0f/(float)B2, rB = 1.0f/(float)B;
    for (int cb = (lane >> 4); cb < nbox; cb += 4){
      int dz = (int)(((float)cb + 0.5f)*rB2);
      int r2 = cb - dz*B2;
      int dy = (int)(((float)r2 + 0.5f)*rB);
      int dx = r2 - dy*B;
      dx -= s; dy -= s; dz -= s;
      int ax = dx<0?-dx:dx, ay = dy<0?-dy:dy, az = dz<0?-dz:dz;
      int ch = ax>ay?ax:ay; ch = ch>az?ch:az;
      if (ch != s) continue;               // interior done in earlier shells
      int cx = c0x+dx, cy = c0y+dy, cz = c0z+dz;
      if (cx<0 || cx>=g.gx || cy<0 || cy>=g.gy || cz<0 || cz>=g.gz) continue;
      int cid = (cz*g.gy + cy)*g.gx + cx;
      int nc = (int)fill[cid];
      int nreal = nc > MAXPC ? MAXPC : nc;
      if (slotm >= nreal) continue;
      if (hasu){
        float lox = g.bx + cx*g.csx, loy = g.by + cy*g.csy, loz = g.bz + cz*g.csz;
        float dxx = fmaxf(fmaxf(lox - qv.x, qv.x - (lox + g.csx)), 0.f);
        float dyy = fmaxf(fmaxf(loy - qv.y, qv.y - (loy + g.csy)), 0.f);
        float dzz = fmaxf(fmaxf(loz - qv.z, qv.z - (loz + g.csz)), 0.f);
        float lb = dxx*dxx + dyy*dyy + dzz*dzz;
        if (lb > u + 0.01f) continue;      // margin covers fp in lb/d2
      }
      int gi = (int)cellIdx[cid*MAXPC + slotm];
      float4 cp = candP[gi];
      float d2;
      {
#pragma clang fp contract(off)
        float dot = qv.x*cp.x + qv.y*cp.y + qv.z*cp.z;
        d2 = (qv.w + cp.w) - 2.0f*dot;
      }
      if (d2 < td[3] || (d2 == td[3] && gi < ti[3])) lex_insert<4>(td, ti, d2, gi);
    }
    // refresh upper bound: KSEL-th smallest of per-lane minima
    unsigned long long bal = __ballot(ti[0] != INT_MAX);
    if (__popcll(bal) >= KSEL){
      float v = td[0];
      sort64f1(v, lane);
      u = __shfl(v, KSEL-1);
      hasu = true;
    }
    // full-coverage break
    bool cov = (c0x-s <= 0) && (c0x+s >= g.gx-1) &&
               (c0y-s <= 0) && (c0y+s >= g.gy-1) &&
               (c0z-s <= 0) && (c0z+s >= g.gz-1);
    if (cov) break;
    // distance-bound break: everything outside B_s is provably > u
    if (hasu){
      float m = fminf(qv.x - (g.bx + (c0x-s)*g.csx), (g.bx + (c0x+s+1)*g.csx) - qv.x);
      m = fminf(m, fminf(qv.y - (g.by + (c0y-s)*g.csy), (g.by + (c0y+s+1)*g.csy) - qv.y));
      m = fminf(m, fminf(qv.z - (g.bz + (c0z-s)*g.csz), (g.bz + (c0z+s+1)*g.csz) - qv.z));
      float mm = m - 0.01f;
      if (mm > 0.f && u <= mm*mm) break;
    }
  }

  // ---------------- validity + extraction ----------------
  bool fb = !hasu;
  if (!fb) fb = (__ballot(td[3] <= u) != 0ULL);   // possible hidden 5th
  int C = 0;
  if (!fb){
    const unsigned long long ltm = (1ULL << lane) - 1ULL;
    #pragma unroll
    for (int t=0;t<4;++t){
      bool keep = (td[t] <= u);
      unsigned long long m = __ballot(keep);
      if (keep){
        int o = C + __popcll(m & ltm);
        if (o < 64){ sdd[w][o] = td[t]; sii[w][o] = ti[t]; }
      }
      C += __popcll(m);
    }
    if (C > 64 || C < KSEL) fb = true;
  }

  if (!fb){
    __threadfence_block();
    float dd = FLT_MAX; int gg = INT_MAX;
    if (lane < C){ dd = sdd[w][lane]; gg = sii[w][lane]; }
    sort64pair(dd, gg, lane);
    if (lane >= OUT_OFF && lane < OUT_OFF + KOUT){
      float4 cp = candP[gg];
      float dist;
      {
#pragma clang fp contract(off)
        float dx = qv.x-cp.x, dy = qv.y-cp.y, dz = qv.z-cp.z;
        dist = (dx*dx + dy*dy) + dz*dz;
      }
      oidx[(size_t)q*KOUT + (lane-OUT_OFF)]  = gg;
      odist[(size_t)q*KOUT + (lane-OUT_OFF)] = dist;
    }
    return;
  }

  // ---------------- wave-parallel exact fallback (R9 logic) ----------------
  {
    const float q2x = -2.f*qv.x, q2y = -2.f*qv.y, q2z = -2.f*qv.z;
    float m = FLT_MAX;
    for (int j = lane; j < ncand; j += 64){
      float4 cp = candP[j];
      float e = fmaf(q2x, cp.x, fmaf(q2y, cp.y, fmaf(q2z, cp.z, cp.w)));
      m = fminf(m, e);
    }
    sort64f1(m, lane);
    const float T = __shfl(m, KSEL-1) + MARGIN;

    int cnt = 0;
    const unsigned long long ltm = (1ULL << lane) - 1ULL;
    for (int j = lane; j < ncand; j += 64){
      float4 cp = candP[j];
      float e = fmaf(q2x, cp.x, fmaf(q2y, cp.y, fmaf(q2z, cp.z, cp.w)));
      bool acc = e <= T;
      unsigned long long msk = __ballot(acc);
      if (acc){
        int ofs = cnt + __popcll(msk & ltm);
        if (ofs < 64) sii[w][ofs] = j;
      }
      cnt += __popcll(msk);
    }
    __threadfence_block();

    if (cnt <= 64){
      float dd = FLT_MAX; int gg = INT_MAX;
      if (lane < cnt){
        gg = sii[w][lane];
        float4 cp = candP[gg];
        {
#pragma clang fp contract(off)
          float dot = qv.x*cp.x + qv.y*cp.y + qv.z*cp.z;
          dd = (qv.w + cp.w) - 2.0f*dot;
        }
      }
      sort64pair(dd, gg, lane);
      if (lane >= OUT_OFF && lane < OUT_OFF + KOUT){
        float4 cp = candP[gg];
        float dist;
        {
#pragma clang fp contract(off)
          float dx = qv.x-cp.x, dy = qv.y-cp.y, dz = qv.z-cp.z;
          dist = (dx*dx + dy*dy) + dz*dz;
        }
        oidx[(size_t)q*KOUT + (lane-OUT_OFF)]  = gg;
        odist[(size_t)q*KOUT + (lane-OUT_OFF)] = dist;
      }
    } else if (lane == 0){
      // astronomically rare slot overflow: serial exact full scan
      float bd[KSEL]; int bi[KSEL];
      #pragma unroll
      for (int t=0;t<KSEL;t++){ bd[t]=FLT_MAX; bi[t]=INT_MAX; }
      float cmd = FLT_MAX; int cmi = INT_MAX;
      for (int jj = 0; jj < ncand; ++jj){
        float4 cp = candP[jj];
        float d2;
        {
#pragma clang fp contract(off)
          float dot = qv.x*cp.x + qv.y*cp.y + qv.z*cp.z;
          d2 = (qv.w + cp.w) - 2.0f*dot;
        }
        if (d2 < cmd || (d2 == cmd && jj < cmi)){
          int rt = 0; float rmd=-FLT_MAX; int rmi=-1;
          for (int t=0;t<KSEL;t++){
            if (bd[t] > rmd || (bd[t]==rmd && bi[t]>rmi)){ rmd=bd[t]; rmi=bi[t]; rt=t; }
          }
          bd[rt]=d2; bi[rt]=jj;
          cmd=-FLT_MAX; cmi=-1;
          for (int t=0;t<KSEL;t++){
            if (bd[t] > cmd || (bd[t]==cmd && bi[t]>cmi)){ cmd=bd[t]; cmi=bi[t]; }
          }
        }
      }
      for (int t=0;t<KSEL;t++){
        int rt=-1; float mnd=FLT_MAX; int mni=INT_MAX;
        for (int u2=0;u2<KSEL;u2++){
          if (bd[u2] < mnd || (bd[u2]==mnd && bi[u2]<mni)){ mnd=bd[u2]; mni=bi[u2]; rt=u2; }
        }
        bd[rt]=FLT_MAX; bi[rt]=INT_MAX;
        if (t >= OUT_OFF){
          float4 cp = candP[mni];
          float dist;
          {
#pragma clang fp contract(off)
            float dx=qv.x-cp.x, dy=qv.y-cp.y, dz=qv.z-cp.z;
            dist = (dx*dx + dy*dy) + dz*dz;
          }
          oidx[(size_t)q*KOUT + (t-OUT_OFF)]  = mni;
          odist[(size_t)q*KOUT + (t-OUT_OFF)] = dist;
        }
      }
    }
  }
}

// One message-passing block: out = self + lrelu(groupnorm(sum_k MLP(feat_k)))
// 4 threads per point: each handles 4 of the 16 neighbors, shfl-reduce.
template<bool SELF_ONES>
__global__ __launch_bounds__(256)
void mp_kernel(const float* __restrict__ self_feat,
               const float* __restrict__ nb_src,
               const int* __restrict__ idx,
               const float* __restrict__ dists,
               const float* __restrict__ w1g, const float* __restrict__ b1g,
               const float* __restrict__ w2g, const float* __restrict__ b2g,
               const float* __restrict__ gam, const float* __restrict__ bet,
               float* __restrict__ out, int n){
  __shared__ float w1[H*H], b1v[H], w2[D*H], b2v[D], gm[D], bt[D];
  for (int t=threadIdx.x; t<H*H; t+=blockDim.x) w1[t]=w1g[t];
  if (threadIdx.x < H) b1v[threadIdx.x]=b1g[threadIdx.x];
  for (int t=threadIdx.x; t<D*H; t+=blockDim.x) w2[t]=w2g[t];
  if (threadIdx.x < D){
    b2v[threadIdx.x]=b2g[threadIdx.x];
    gm[threadIdx.x]=gam[threadIdx.x];
    bt[threadIdx.x]=bet[threadIdx.x];
  }
  __syncthreads();
  int tt = blockIdx.x*blockDim.x + threadIdx.x;
  int p = tt >> 2, sub = tt & 3;
  if (p >= n) return;

  float s[D];
  #pragma unroll
  for (int j=0;j<D;j++) s[j] = SELF_ONES ? 1.0f : self_feat[p*D+j];
  float msg[D] = {0,0,0,0,0,0};

  #pragma unroll
  for (int u=0;u<KOUT/4;u++){
    int k = u*4 + sub;
    int j = idx[p*KOUT+k];
    float dd = dists[p*KOUT+k];
    float f[H];
    #pragma unroll
    for (int c=0;c<D;c++) f[c]=s[c];
    #pragma unroll
    for (int c=0;c<D;c++) f[D+c]=nb_src[j*D+c];
    f[2*D]=dd;
    float h[H];
    #pragma unroll
    for (int o=0;o<H;o++){
      float acc=b1v[o];
      #pragma unroll
      for (int c=0;c<H;c++) acc += w1[o*H+c]*f[c];
      h[o]=lrelu(acc);
    }
    #pragma unroll
    for (int o=0;o<D;o++){
      float acc=b2v[o];
      #pragma unroll
      for (int c=0;c<H;c++) acc += w2[o*H+c]*h[c];
      msg[o]+=acc;
    }
  }

  #pragma unroll
  for (int c=0;c<D;c++){
    msg[c] += __shfl_xor(msg[c], 1);
    msg[c] += __shfl_xor(msg[c], 2);
  }

  if (sub == 0){
    float y[D];
    #pragma unroll
    for (int gi=0; gi<2; gi++){
      float m0=msg[gi*3+0], m1=msg[gi*3+1], m2=msg[gi*3+2];
      float mu = ((m0+m1)+m2) / 3.0f;
      float d0=m0-mu, d1=m1-mu, d2v=m2-mu;
      float var = ((d0*d0 + d1*d1) + d2v*d2v) / 3.0f;
      float inv = 1.0f / sqrtf(var + GEPS);
      y[gi*3+0] = d0*inv;
      y[gi*3+1] = d1*inv;
      y[gi*3+2] = d2v*inv;
    }
    #pragma unroll
    for (int c=0;c<D;c++){
      float vv = y[c]*gm[c] + bt[c];
      out[p*D+c] = s[c] + lrelu(vv);
    }
  }
}

extern "C" void kernel_launch(void* const* d_in, const int* in_sizes, int n_in,
                              void* d_out, int out_size, void* d_ws, size_t ws_size,
                              hipStream_t stream){
  const float* xyz       = (const float*)d_in[0];
  const float* atom_xyz  = (const float*)d_in[1];
  const float* atomtypes = (const float*)d_in[2];
  const float* tt_w1 = (const float*)d_in[5];
  const float* tt_b1 = (const float*)d_in[6];
  const float* tt_w2 = (const float*)d_in[7];
  const float* tt_b2 = (const float*)d_in[8];
  const float* aa_w1 = (const float*)d_in[9];
  const float* aa_b1 = (const float*)d_in[10];
  const float* aa_w2 = (const float*)d_in[11];
  const float* aa_b2 = (const float*)d_in[12];
  const float* aa_gamma = (const float*)d_in[13];
  const float* aa_beta  = (const float*)d_in[14];
  const float* em_w1 = (const float*)d_in[15];
  const float* em_b1 = (const float*)d_in[16];
  const float* em_w2 = (const float*)d_in[17];
  const float* em_b2 = (const float*)d_in[18];
  const float* em_gamma = (const float*)d_in[19];
  const float* em_beta  = (const float*)d_in[20];

  const int n_pts = in_sizes[0]/3;
  const int n_at  = in_sizes[1]/3;

  char* ws = (char*)d_ws;
  float4* candP = (float4*)ws; ws += (size_t)n_at*sizeof(float4);
  float4* ptsP  = (float4*)ws; ws += (size_t)n_pts*sizeof(float4);
  float* fa   = (float*)ws; ws += (size_t)n_at*D*4;
  float* fb   = (float*)ws; ws += (size_t)n_at*D*4;
  int*   idxA = (int*)ws;   ws += (size_t)n_at*KOUT*4;
  float* distA= (float*)ws; ws += (size_t)n_at*KOUT*4;
  int*   idxP = (int*)ws;   ws += (size_t)n_pts*KOUT*4;
  float* distP= (float*)ws; ws += (size_t)n_pts*KOUT*4;
  float* ea   = (float*)ws; ws += (size_t)n_pts*D*4;
  float* eb   = (float*)ws; ws += (size_t)n_pts*D*4;
  unsigned* bbx   = (unsigned*)ws; ws += 8*4;
  unsigned* spCnt = (unsigned*)ws; ws += 8*4;
  unsigned* fill  = (unsigned*)ws; ws += (size_t)MAXC*4;
  ushort* cellIdx = (ushort*)ws;   ws += (size_t)MAXC*MAXPC*2;
  ushort* spill   = (ushort*)ws;   ws += (size_t)8192*2;
  float* outf = (float*)d_out;

  // ---- grid build ----
  init_kernel<<<(MAXC+255)/256,256,0,stream>>>(bbx, fill, spCnt);
  bbox_kernel<<<(n_at+255)/256,256,0,stream>>>(atom_xyz, n_at, bbx);
  scatter_kernel<<<(n_at+255)/256,256,0,stream>>>(atom_xyz, n_at, bbx, fill, cellIdx, spill, spCnt);

  pack_kernel<<<(n_at +255)/256,256,0,stream>>>(atom_xyz, candP, n_at);
  pack_kernel<<<(n_pts+255)/256,256,0,stream>>>(xyz, ptsP, n_pts);

  tt_kernel<<<(n_at+255)/256,256,0,stream>>>(atomtypes, tt_w1,tt_b1,tt_w2,tt_b2, fa, n_at);

  // ---- atom-atom KNN (k=17, drop self) ----
  knn_grid2_kernel<17,1><<<(n_at+WPB-1)/WPB,256,0,stream>>>(
      candP, n_at, candP, n_at, bbx, fill, cellIdx, spill, spCnt, idxA, distA);

  mp_kernel<false><<<(n_at*4+255)/256,256,0,stream>>>(fa, fa, idxA, distA,
      aa_w1+0*H*H, aa_b1+0*H, aa_w2+0*D*H, aa_b2+0*D, aa_gamma+0*D, aa_beta+0*D, fb, n_at);
  mp_kernel<false><<<(n_at*4+255)/256,256,0,stream>>>(fb, fb, idxA, distA,
      aa_w1+1*H*H, aa_b1+1*H, aa_w2+1*D*H, aa_b2+1*D, aa_gamma+1*D, aa_beta+1*D, fa, n_at);
  mp_kernel<false><<<(n_at*4+255)/256,256,0,stream>>>(fa, fa, idxA, distA,
      aa_w1+2*H*H, aa_b1+2*H, aa_w2+2*D*H, aa_b2+2*D, aa_gamma+2*D, aa_beta+2*D, fb, n_at);
  // final atom features in fb

  // ---- point-atom KNN (k=16) ----
  knn_grid2_kernel<16,0><<<(n_pts+WPB-1)/WPB,256,0,stream>>>(
      candP, n_at, ptsP, n_pts, bbx, fill, cellIdx, spill, spCnt, idxP, distP);

  mp_kernel<true ><<<(n_pts*4+255)/256,256,0,stream>>>(nullptr, fb, idxP, distP,
      em_w1+0*H*H, em_b1+0*H, em_w2+0*D*H, em_b2+0*D, em_gamma+0*D, em_beta+0*D, ea, n_pts);
  mp_kernel<false><<<(n_pts*4+255)/256,256,0,stream>>>(ea, fb, idxP, distP,
      em_w1+1*H*H, em_b1+1*H, em_w2+1*D*H, em_b2+1*D, em_gamma+1*D, em_beta+1*D, eb, n_pts);
  mp_kernel<false><<<(n_pts*4+255)/256,256,0,stream>>>(eb, fb, idxP, distP,
      em_w1+2*H*H, em_b1+2*H, em_w2+2*D*H, em_b2+2*D, em_gamma+2*D, em_beta+2*D, outf, n_pts);
}

// Round 13
// 205.850 us; speedup vs baseline: 66.7076x; 66.7076x over previous
//
#include <hip/hip_runtime.h>
#include <cfloat>
#include <climits>

#define NEG 0.2f
#define GEPS 1e-5f
#define D 6
#define H 13   // 2*D+1
#define KOUT 16

#define MPAD 8192      // padded candidate capacity (NTILES*TILE)
#define TILE 1024      // candidates per LDS tile (16 KB)
#define NTILES 8       // MPAD / TILE
#define QW 4           // queries per wave
#define QBLK 16        // queries per block (4 waves)
#define CAP 64         // survivor slots per query
#define MARGIN 0.05f   // e-space margin covering fma-vs-reference rounding

__device__ __forceinline__ float lrelu(float x){ return x >= 0.f ? x : NEG*x; }

// atoms (n,3) -> P {x,y,z,|c|^2}, padded with never-selected sentinels
__global__ void pack_kernel(const float* __restrict__ xyz,
                            float4* __restrict__ P, int n, int npad){
  int i = blockIdx.x*blockDim.x + threadIdx.x;
  if (i >= npad) return;
  if (i < n){
    float x = xyz[3*i], y = xyz[3*i+1], z = xyz[3*i+2];
    float sq;
    {
#pragma clang fp contract(off)
      sq = (x*x + y*y) + z*z;
    }
    P[i] = make_float4(x,y,z,sq);
  } else {
    P[i] = make_float4(0.f,0.f,0.f,1e30f);  // e = 1e30 -> never a min/survivor
  }
}

// atomtypes (n,6) -> 2-layer MLP -> out (n,6)
__global__ void tt_kernel(const float* __restrict__ at_in,
                          const float* __restrict__ w1, const float* __restrict__ b1,
                          const float* __restrict__ w2, const float* __restrict__ b2,
                          float* __restrict__ out, int n){
  int i = blockIdx.x*blockDim.x + threadIdx.x;
  if (i >= n) return;
  float x[D], h[D];
  #pragma unroll
  for (int j=0;j<D;j++) x[j] = at_in[i*D+j];
  #pragma unroll
  for (int o=0;o<D;o++){
    float acc = b1[o];
    #pragma unroll
    for (int j=0;j<D;j++) acc += w1[o*D+j]*x[j];
    h[o] = lrelu(acc);
  }
  #pragma unroll
  for (int o=0;o<D;o++){
    float acc = b2[o];
    #pragma unroll
    for (int j=0;j<D;j++) acc += w2[o*D+j]*h[j];
    out[i*D+o] = acc;
  }
}

// QW independent ascending value-sorts across 64 lanes (ILP-batched)
__device__ __forceinline__ void sort64fq(float (&v)[QW], int lane){
  #pragma unroll
  for (int k = 2; k <= 64; k <<= 1){
    #pragma unroll
    for (int j = k >> 1; j >= 1; j >>= 1){
      bool dir = ((lane & j) == 0) == ((lane & k) == 0);
      #pragma unroll
      for (int q = 0; q < QW; ++q){
        float o = __shfl_xor(v[q], j);
        v[q] = dir ? fminf(v[q], o) : fmaxf(v[q], o);
      }
    }
  }
}

// ascending lexicographic (d, i) bitonic sort across 64 lanes
__device__ __forceinline__ void sort64pair(float& d, int& i, int lane){
  #pragma unroll
  for (int k = 2; k <= 64; k <<= 1){
    #pragma unroll
    for (int j = k >> 1; j >= 1; j >>= 1){
      float od = __shfl_xor(d, j);
      int   oi = __shfl_xor(i, j);
      bool lower = (lane & j) == 0;
      bool asc   = (lane & k) == 0;
      bool oless = (od < d) || (od == d && oi < i);
      bool take  = (lower == asc) ? oless : !oless;
      d = take ? od : d;
      i = take ? oi : i;
    }
  }
}

// KNN v8: R9's proven selection machinery with candidates staged in LDS
// tiles, cooperatively loaded once per block (4 waves share one stream
// instead of four private L2 streams). Lane-set partition is unchanged
// ({j : j%64 == lane}), so the threshold proof is identical to R9:
// T(q) = KSEL-th smallest of 64 per-lane e-mins (64 disjoint witnesses)
// + MARGIN. Pass 2: survivors -> per-(wave,query) LDS slots via rare-path
// atomicAdd (unordered; phase 3 sorts). Phase 3: exact contract-off lex
// (d2, idx) sort across lanes, emit KOUT from OUT_OFF.
template<int KSEL, int OUT_OFF>
__global__ __launch_bounds__(256)
void knn8_kernel(const float4* __restrict__ candP, int ncand,
                 const float4* __restrict__ qarr, int nq,
                 int* __restrict__ oidx, float* __restrict__ odist){
  __shared__ float4 tile[TILE];            // 16 KB
  __shared__ float4 qs[QBLK];
  __shared__ ushort slots[4][QW][CAP];
  __shared__ int    scnt[4][QW];

  const int tid  = threadIdx.x;
  const int w    = tid >> 6;
  const int lane = tid & 63;

  if (tid < QBLK){
    int qg = blockIdx.x*QBLK + tid;
    qs[tid] = qarr[qg < nq ? qg : nq-1];   // clamp: all waves stay full
  }
  if (lane < QW) scnt[w][lane] = 0;
  __syncthreads();

  // -2*q in registers (e = fma(q2x,cx, fma(q2y,cy, fma(q2z,cz, cw))))
  float q2x[QW], q2y[QW], q2z[QW];
  #pragma unroll
  for (int q = 0; q < QW; ++q){
    float4 v = qs[w*QW + q];
    q2x[q] = -2.f*v.x; q2y[q] = -2.f*v.y; q2z[q] = -2.f*v.z;
  }

  // ---------------- pass 1: per-lane e-min per query (LDS-tiled) ---------
  float mn[QW];
  #pragma unroll
  for (int q = 0; q < QW; ++q) mn[q] = FLT_MAX;

  for (int t = 0; t < NTILES; ++t){
    #pragma unroll
    for (int u = 0; u < TILE/256; ++u)
      tile[tid + 256*u] = candP[t*TILE + tid + 256*u];
    __syncthreads();
    #pragma unroll 4
    for (int i = 0; i < TILE/64; ++i){
      float4 cv = tile[i*64 + lane];
      #pragma unroll
      for (int q = 0; q < QW; ++q){
        float e = fmaf(q2x[q], cv.x, fmaf(q2y[q], cv.y, fmaf(q2z[q], cv.z, cv.w)));
        mn[q] = fminf(mn[q], e);
      }
    }
    __syncthreads();
  }

  // threshold per query: KSEL-th smallest lane-min + margin
  sort64fq(mn, lane);
  float T[QW];
  #pragma unroll
  for (int q = 0; q < QW; ++q) T[q] = __shfl(mn[q], KSEL-1) + MARGIN;

  // ---------------- pass 2: collect survivors (LDS-tiled) ----------------
  for (int t = 0; t < NTILES; ++t){
    #pragma unroll
    for (int u = 0; u < TILE/256; ++u)
      tile[tid + 256*u] = candP[t*TILE + tid + 256*u];
    __syncthreads();
    #pragma unroll 4
    for (int i = 0; i < TILE/64; ++i){
      float4 cv = tile[i*64 + lane];
      const int j = t*TILE + i*64 + lane;
      #pragma unroll
      for (int q = 0; q < QW; ++q){
        float e = fmaf(q2x[q], cv.x, fmaf(q2y[q], cv.y, fmaf(q2z[q], cv.z, cv.w)));
        if (e <= T[q]){
          int ofs = atomicAdd(&scnt[w][q], 1);
          if (ofs < CAP) slots[w][q][ofs] = (ushort)j;
        }
      }
    }
    __syncthreads();
  }

  // ---------------- phase 3: exact per-query select ----------------
  for (int q = 0; q < QW; ++q){
    const int qgq = blockIdx.x*QBLK + w*QW + q;
    if (qgq >= nq) continue;                 // wave-uniform
    const float4 qv = qs[w*QW + q];
    const int C = scnt[w][q];

    if (C <= CAP){
      int g = INT_MAX; float d2 = FLT_MAX;
      if (lane < C){
        g = slots[w][q][lane];
        float4 cp = candP[g];
        {
#pragma clang fp contract(off)
          float dot = qv.x*cp.x + qv.y*cp.y + qv.z*cp.z;
          d2 = (qv.w + cp.w) - 2.0f*dot;
        }
      }
      sort64pair(d2, g, lane);
      if (lane >= OUT_OFF && lane < OUT_OFF + KOUT){
        float4 cp = candP[g];
        float dist;
        {
#pragma clang fp contract(off)
          float dx = qv.x-cp.x, dy = qv.y-cp.y, dz = qv.z-cp.z;
          dist = (dx*dx + dy*dy) + dz*dz;
        }
        oidx[(size_t)qgq*KOUT + (lane-OUT_OFF)]  = g;
        odist[(size_t)qgq*KOUT + (lane-OUT_OFF)] = dist;
      }
    } else if (lane == 0){
      // astronomically rare slot overflow: serial exact full scan
      float bd[KSEL]; int bi[KSEL];
      #pragma unroll
      for (int t=0;t<KSEL;t++){ bd[t]=FLT_MAX; bi[t]=INT_MAX; }
      float cmd = FLT_MAX; int cmi = INT_MAX;
      for (int jj = 0; jj < ncand; ++jj){
        float4 cp = candP[jj];
        float d2;
        {
#pragma clang fp contract(off)
          float dot = qv.x*cp.x + qv.y*cp.y + qv.z*cp.z;
          d2 = (qv.w + cp.w) - 2.0f*dot;
        }
        if (d2 < cmd || (d2 == cmd && jj < cmi)){
          int rt = 0; float rmd=-FLT_MAX; int rmi=-1;
          for (int t=0;t<KSEL;t++){
            if (bd[t] > rmd || (bd[t]==rmd && bi[t]>rmi)){ rmd=bd[t]; rmi=bi[t]; rt=t; }
          }
          bd[rt]=d2; bi[rt]=jj;
          cmd=-FLT_MAX; cmi=-1;
          for (int t=0;t<KSEL;t++){
            if (bd[t] > cmd || (bd[t]==cmd && bi[t]>cmi)){ cmd=bd[t]; cmi=bi[t]; }
          }
        }
      }
      for (int t=0;t<KSEL;t++){
        int rt=-1; float mnd=FLT_MAX; int mni=INT_MAX;
        for (int u2=0;u2<KSEL;u2++){
          if (bd[u2] < mnd || (bd[u2]==mnd && bi[u2]<mni)){ mnd=bd[u2]; mni=bi[u2]; rt=u2; }
        }
        bd[rt]=FLT_MAX; bi[rt]=INT_MAX;
        if (t >= OUT_OFF){
          float4 cp = candP[mni];
          float dist;
          {
#pragma clang fp contract(off)
            float dx=qv.x-cp.x, dy=qv.y-cp.y, dz=qv.z-cp.z;
            dist = (dx*dx + dy*dy) + dz*dz;
          }
          oidx[(size_t)qgq*KOUT + (t-OUT_OFF)]  = mni;
          odist[(size_t)qgq*KOUT + (t-OUT_OFF)] = dist;
        }
      }
    }
  }
}

// One message-passing block: out = self + lrelu(groupnorm(sum_k MLP(feat_k)))
// 4 threads per point: each handles 4 of the 16 neighbors, shfl-reduce.
template<bool SELF_ONES>
__global__ __launch_bounds__(256)
void mp_kernel(const float* __restrict__ self_feat,
               const float* __restrict__ nb_src,
               const int* __restrict__ idx,
               const float* __restrict__ dists,
               const float* __restrict__ w1g, const float* __restrict__ b1g,
               const float* __restrict__ w2g, const float* __restrict__ b2g,
               const float* __restrict__ gam, const float* __restrict__ bet,
               float* __restrict__ out, int n){
  __shared__ float w1[H*H], b1v[H], w2[D*H], b2v[D], gm[D], bt[D];
  for (int t=threadIdx.x; t<H*H; t+=blockDim.x) w1[t]=w1g[t];
  if (threadIdx.x < H) b1v[threadIdx.x]=b1g[threadIdx.x];
  for (int t=threadIdx.x; t<D*H; t+=blockDim.x) w2[t]=w2g[t];
  if (threadIdx.x < D){
    b2v[threadIdx.x]=b2g[threadIdx.x];
    gm[threadIdx.x]=gam[threadIdx.x];
    bt[threadIdx.x]=bet[threadIdx.x];
  }
  __syncthreads();
  int tt = blockIdx.x*blockDim.x + threadIdx.x;
  int p = tt >> 2, sub = tt & 3;
  if (p >= n) return;

  float s[D];
  #pragma unroll
  for (int j=0;j<D;j++) s[j] = SELF_ONES ? 1.0f : self_feat[p*D+j];
  float msg[D] = {0,0,0,0,0,0};

  #pragma unroll
  for (int u=0;u<KOUT/4;u++){
    int k = u*4 + sub;
    int j = idx[p*KOUT+k];
    float dd = dists[p*KOUT+k];
    float f[H];
    #pragma unroll
    for (int c=0;c<D;c++) f[c]=s[c];
    #pragma unroll
    for (int c=0;c<D;c++) f[D+c]=nb_src[j*D+c];
    f[2*D]=dd;
    float h[H];
    #pragma unroll
    for (int o=0;o<H;o++){
      float acc=b1v[o];
      #pragma unroll
      for (int c=0;c<H;c++) acc += w1[o*H+c]*f[c];
      h[o]=lrelu(acc);
    }
    #pragma unroll
    for (int o=0;o<D;o++){
      float acc=b2v[o];
      #pragma unroll
      for (int c=0;c<H;c++) acc += w2[o*H+c]*h[c];
      msg[o]+=acc;
    }
  }

  #pragma unroll
  for (int c=0;c<D;c++){
    msg[c] += __shfl_xor(msg[c], 1);
    msg[c] += __shfl_xor(msg[c], 2);
  }

  if (sub == 0){
    float y[D];
    #pragma unroll
    for (int gi=0; gi<2; gi++){
      float m0=msg[gi*3+0], m1=msg[gi*3+1], m2=msg[gi*3+2];
      float mu = ((m0+m1)+m2) / 3.0f;
      float d0=m0-mu, d1=m1-mu, d2v=m2-mu;
      float var = ((d0*d0 + d1*d1) + d2v*d2v) / 3.0f;
      float inv = 1.0f / sqrtf(var + GEPS);
      y[gi*3+0] = d0*inv;
      y[gi*3+1] = d1*inv;
      y[gi*3+2] = d2v*inv;
    }
    #pragma unroll
    for (int c=0;c<D;c++){
      float vv = y[c]*gm[c] + bt[c];
      out[p*D+c] = s[c] + lrelu(vv);
    }
  }
}

extern "C" void kernel_launch(void* const* d_in, const int* in_sizes, int n_in,
                              void* d_out, int out_size, void* d_ws, size_t ws_size,
                              hipStream_t stream){
  const float* xyz       = (const float*)d_in[0];
  const float* atom_xyz  = (const float*)d_in[1];
  const float* atomtypes = (const float*)d_in[2];
  const float* tt_w1 = (const float*)d_in[5];
  const float* tt_b1 = (const float*)d_in[6];
  const float* tt_w2 = (const float*)d_in[7];
  const float* tt_b2 = (const float*)d_in[8];
  const float* aa_w1 = (const float*)d_in[9];
  const float* aa_b1 = (const float*)d_in[10];
  const float* aa_w2 = (const float*)d_in[11];
  const float* aa_b2 = (const float*)d_in[12];
  const float* aa_gamma = (const float*)d_in[13];
  const float* aa_beta  = (const float*)d_in[14];
  const float* em_w1 = (const float*)d_in[15];
  const float* em_b1 = (const float*)d_in[16];
  const float* em_w2 = (const float*)d_in[17];
  const float* em_b2 = (const float*)d_in[18];
  const float* em_gamma = (const float*)d_in[19];
  const float* em_beta  = (const float*)d_in[20];

  const int n_pts = in_sizes[0]/3;
  const int n_at  = in_sizes[1]/3;

  char* ws = (char*)d_ws;
  float4* candP = (float4*)ws; ws += (size_t)MPAD*sizeof(float4);
  float4* ptsP  = (float4*)ws; ws += (size_t)n_pts*sizeof(float4);
  float* fa   = (float*)ws; ws += (size_t)n_at*D*4;
  float* fb   = (float*)ws; ws += (size_t)n_at*D*4;
  int*   idxA = (int*)ws;   ws += (size_t)n_at*KOUT*4;
  float* distA= (float*)ws; ws += (size_t)n_at*KOUT*4;
  int*   idxP = (int*)ws;   ws += (size_t)n_pts*KOUT*4;
  float* distP= (float*)ws; ws += (size_t)n_pts*KOUT*4;
  float* ea   = (float*)ws; ws += (size_t)n_pts*D*4;
  float* eb   = (float*)ws; ws += (size_t)n_pts*D*4;
  float* outf = (float*)d_out;

  pack_kernel<<<(MPAD+255)/256,256,0,stream>>>(atom_xyz, candP, n_at, MPAD);
  pack_kernel<<<(n_pts+255)/256,256,0,stream>>>(xyz, ptsP, n_pts, n_pts);

  tt_kernel<<<(n_at+255)/256,256,0,stream>>>(atomtypes, tt_w1,tt_b1,tt_w2,tt_b2, fa, n_at);

  // ---- atom-atom KNN (k=17, drop self) ----
  knn8_kernel<17,1><<<(n_at+QBLK-1)/QBLK,256,0,stream>>>(
      candP, n_at, candP, n_at, idxA, distA);

  mp_kernel<false><<<(n_at*4+255)/256,256,0,stream>>>(fa, fa, idxA, distA,
      aa_w1+0*H*H, aa_b1+0*H, aa_w2+0*D*H, aa_b2+0*D, aa_gamma+0*D, aa_beta+0*D, fb, n_at);
  mp_kernel<false><<<(n_at*4+255)/256,256,0,stream>>>(fb, fb, idxA, distA,
      aa_w1+1*H*H, aa_b1+1*H, aa_w2+1*D*H, aa_b2+1*D, aa_gamma+1*D, aa_beta+1*D, fa, n_at);
  mp_kernel<false><<<(n_at*4+255)/256,256,0,stream>>>(fa, fa, idxA, distA,
      aa_w1+2*H*H, aa_b1+2*H, aa_w2+2*D*H, aa_b2+2*D, aa_gamma+2*D, aa_beta+2*D, fb, n_at);
  // final atom features in fb

  // ---- point-atom KNN (k=16) ----
  knn8_kernel<16,0><<<(n_pts+QBLK-1)/QBLK,256,0,stream>>>(
      candP, n_at, ptsP, n_pts, idxP, distP);

  mp_kernel<true ><<<(n_pts*4+255)/256,256,0,stream>>>(nullptr, fb, idxP, distP,
      em_w1+0*H*H, em_b1+0*H, em_w2+0*D*H, em_b2+0*D, em_gamma+0*D, em_beta+0*D, ea, n_pts);
  mp_kernel<false><<<(n_pts*4+255)/256,256,0,stream>>>(ea, fb, idxP, distP,
      em_w1+1*H*H, em_b1+1*H, em_w2+1*D*H, em_b2+1*D, em_gamma+1*D, em_beta+1*D, eb, n_pts);
  mp_kernel<false><<<(n_pts*4+255)/256,256,0,stream>>>(eb, fb, idxP, distP,
      em_w1+2*H*H, em_b1+2*H, em_w2+2*D*H, em_b2+2*D, em_gamma+2*D, em_beta+2*D, outf, n_pts);
}

// Round 14
// 162.935 us; speedup vs baseline: 84.2777x; 1.2634x over previous
//
#include <hip/hip_runtime.h>
#include <cfloat>
#include <climits>

#define NEG 0.2f
#define GEPS 1e-5f
#define D 6
#define H 13   // 2*D+1
#define KOUT 16

#define MPAD 8192      // padded candidate capacity (NTILES*TILE)
#define TILE 1024      // candidates per LDS tile (16 KB)
#define NTILES 8       // MPAD / TILE
#define QW 8           // queries per wave
#define QBLK 32        // queries per block (4 waves)
#define CAP 64         // survivor slots per query
#define KMAX 17        // max KSEL (atom task)
#define MARGIN 0.05f   // e-space margin covering fma-vs-reference rounding

__device__ __forceinline__ float lrelu(float x){ return x >= 0.f ? x : NEG*x; }

// atoms (n,3) -> P {x,y,z,|c|^2}, padded with never-selected sentinels
__global__ void pack_kernel(const float* __restrict__ xyz,
                            float4* __restrict__ P, int n, int npad){
  int i = blockIdx.x*blockDim.x + threadIdx.x;
  if (i >= npad) return;
  if (i < n){
    float x = xyz[3*i], y = xyz[3*i+1], z = xyz[3*i+2];
    float sq;
    {
#pragma clang fp contract(off)
      sq = (x*x + y*y) + z*z;
    }
    P[i] = make_float4(x,y,z,sq);
  } else {
    P[i] = make_float4(0.f,0.f,0.f,1e30f);  // e = 1e30 -> never a min/survivor
  }
}

// atomtypes (n,6) -> 2-layer MLP -> out (n,6)
__global__ void tt_kernel(const float* __restrict__ at_in,
                          const float* __restrict__ w1, const float* __restrict__ b1,
                          const float* __restrict__ w2, const float* __restrict__ b2,
                          float* __restrict__ out, int n){
  int i = blockIdx.x*blockDim.x + threadIdx.x;
  if (i >= n) return;
  float x[D], h[D];
  #pragma unroll
  for (int j=0;j<D;j++) x[j] = at_in[i*D+j];
  #pragma unroll
  for (int o=0;o<D;o++){
    float acc = b1[o];
    #pragma unroll
    for (int j=0;j<D;j++) acc += w1[o*D+j]*x[j];
    h[o] = lrelu(acc);
  }
  #pragma unroll
  for (int o=0;o<D;o++){
    float acc = b2[o];
    #pragma unroll
    for (int j=0;j<D;j++) acc += w2[o*D+j]*h[j];
    out[i*D+o] = acc;
  }
}

// QW independent ascending value-sorts across 64 lanes (ILP-batched)
__device__ __forceinline__ void sort64fq(float (&v)[QW], int lane){
  #pragma unroll
  for (int k = 2; k <= 64; k <<= 1){
    #pragma unroll
    for (int j = k >> 1; j >= 1; j >>= 1){
      bool dir = ((lane & j) == 0) == ((lane & k) == 0);
      #pragma unroll
      for (int q = 0; q < QW; ++q){
        float o = __shfl_xor(v[q], j);
        v[q] = dir ? fminf(v[q], o) : fmaxf(v[q], o);
      }
    }
  }
}

// ascending lexicographic (d, i) bitonic sort across 64 lanes
__device__ __forceinline__ void sort64pair(float& d, int& i, int lane){
  #pragma unroll
  for (int k = 2; k <= 64; k <<= 1){
    #pragma unroll
    for (int j = k >> 1; j >= 1; j >>= 1){
      float od = __shfl_xor(d, j);
      int   oi = __shfl_xor(i, j);
      bool lower = (lane & j) == 0;
      bool asc   = (lane & k) == 0;
      bool oless = (od < d) || (od == d && oi < i);
      bool take  = (lower == asc) ? oless : !oless;
      d = take ? od : d;
      i = take ? oi : i;
    }
  }
}

// KNN v9: R13's LDS-tiled two-pass selection with QW=8 (VALU:LDS pipe
// rebalanced to ~16:12 per CU per iter) and BOTH tasks (atom k=17 drop-self,
// point k=16) fused into one dispatch via block-range task selection
// (fills the machine: 875 blocks). Selection machinery identical to R9/R13:
// T(q) = ksel-th smallest of 64 per-lane e-mins (64 disjoint witnesses)
// + MARGIN; survivors -> LDS slots via rare-path atomicAdd (unordered);
// exact contract-off lex (d2,idx) sort across lanes; serial exact fallback
// on (astronomically rare) slot overflow.
__global__ __launch_bounds__(256)
void knn9_kernel(const float4* __restrict__ candP, int ncand,
                 const float4* __restrict__ qarrA, int nqA, int nbA,
                 const float4* __restrict__ qarrB, int nqB,
                 int* __restrict__ oidxA, float* __restrict__ odistA,
                 int* __restrict__ oidxB, float* __restrict__ odistB){
  __shared__ float4 tile[TILE];            // 16 KB
  __shared__ float4 qs[QBLK];
  __shared__ ushort slots[4][QW][CAP];     // 4 KB
  __shared__ int    scnt[4][QW];

  const int tid  = threadIdx.x;
  const int w    = tid >> 6;
  const int lane = tid & 63;

  const bool taskA = (int)blockIdx.x < nbA;
  const int  bq    = taskA ? blockIdx.x : (blockIdx.x - nbA);
  const float4* __restrict__ qarr = taskA ? qarrA : qarrB;
  const int  nq    = taskA ? nqA : nqB;
  const int  ksel  = taskA ? 17 : 16;
  const int  ooff  = taskA ? 1  : 0;
  int*   __restrict__ oidx  = taskA ? oidxA  : oidxB;
  float* __restrict__ odist = taskA ? odistA : odistB;

  if (tid < QBLK){
    int qg = bq*QBLK + tid;
    qs[tid] = qarr[qg < nq ? qg : nq-1];   // clamp: all waves stay full
  }
  if (lane < QW) scnt[w][lane] = 0;
  __syncthreads();

  // -2*q in registers (e = fma(q2x,cx, fma(q2y,cy, fma(q2z,cz, cw))))
  float q2x[QW], q2y[QW], q2z[QW];
  #pragma unroll
  for (int q = 0; q < QW; ++q){
    float4 v = qs[w*QW + q];
    q2x[q] = -2.f*v.x; q2y[q] = -2.f*v.y; q2z[q] = -2.f*v.z;
  }

  // ---------------- pass 1: per-lane e-min per query (LDS-tiled) ---------
  float mn[QW];
  #pragma unroll
  for (int q = 0; q < QW; ++q) mn[q] = FLT_MAX;

  for (int t = 0; t < NTILES; ++t){
    #pragma unroll
    for (int u = 0; u < TILE/256; ++u)
      tile[tid + 256*u] = candP[t*TILE + tid + 256*u];
    __syncthreads();
    #pragma unroll 2
    for (int i = 0; i < TILE/64; ++i){
      float4 cv = tile[i*64 + lane];
      #pragma unroll
      for (int q = 0; q < QW; ++q){
        float e = fmaf(q2x[q], cv.x, fmaf(q2y[q], cv.y, fmaf(q2z[q], cv.z, cv.w)));
        mn[q] = fminf(mn[q], e);
      }
    }
    __syncthreads();
  }

  // threshold per query: ksel-th smallest lane-min + margin
  sort64fq(mn, lane);
  float T[QW];
  #pragma unroll
  for (int q = 0; q < QW; ++q) T[q] = __shfl(mn[q], ksel-1) + MARGIN;

  // ---------------- pass 2: collect survivors (LDS-tiled) ----------------
  for (int t = 0; t < NTILES; ++t){
    #pragma unroll
    for (int u = 0; u < TILE/256; ++u)
      tile[tid + 256*u] = candP[t*TILE + tid + 256*u];
    __syncthreads();
    #pragma unroll 2
    for (int i = 0; i < TILE/64; ++i){
      float4 cv = tile[i*64 + lane];
      const int j = t*TILE + i*64 + lane;
      #pragma unroll
      for (int q = 0; q < QW; ++q){
        float e = fmaf(q2x[q], cv.x, fmaf(q2y[q], cv.y, fmaf(q2z[q], cv.z, cv.w)));
        if (e <= T[q]){
          int ofs = atomicAdd(&scnt[w][q], 1);
          if (ofs < CAP) slots[w][q][ofs] = (ushort)j;
        }
      }
    }
    __syncthreads();
  }

  // ---------------- phase 3: exact per-query select ----------------
  for (int q = 0; q < QW; ++q){
    const int qgq = bq*QBLK + w*QW + q;
    if (qgq >= nq) continue;                 // wave-uniform
    const float4 qv = qs[w*QW + q];
    const int C = scnt[w][q];

    if (C <= CAP){
      int g = INT_MAX; float d2 = FLT_MAX;
      if (lane < C){
        g = slots[w][q][lane];
        float4 cp = candP[g];
        {
#pragma clang fp contract(off)
          float dot = qv.x*cp.x + qv.y*cp.y + qv.z*cp.z;
          d2 = (qv.w + cp.w) - 2.0f*dot;
        }
      }
      sort64pair(d2, g, lane);
      if (lane >= ooff && lane < ooff + KOUT){
        float4 cp = candP[g];
        float dist;
        {
#pragma clang fp contract(off)
          float dx = qv.x-cp.x, dy = qv.y-cp.y, dz = qv.z-cp.z;
          dist = (dx*dx + dy*dy) + dz*dz;
        }
        oidx[(size_t)qgq*KOUT + (lane-ooff)]  = g;
        odist[(size_t)qgq*KOUT + (lane-ooff)] = dist;
      }
    } else if (lane == 0){
      // astronomically rare slot overflow: serial exact full scan
      float bd[KMAX]; int bi[KMAX];
      for (int t=0;t<ksel;t++){ bd[t]=FLT_MAX; bi[t]=INT_MAX; }
      float cmd = FLT_MAX; int cmi = INT_MAX;
      for (int jj = 0; jj < ncand; ++jj){
        float4 cp = candP[jj];
        float d2;
        {
#pragma clang fp contract(off)
          float dot = qv.x*cp.x + qv.y*cp.y + qv.z*cp.z;
          d2 = (qv.w + cp.w) - 2.0f*dot;
        }
        if (d2 < cmd || (d2 == cmd && jj < cmi)){
          int rt = 0; float rmd=-FLT_MAX; int rmi=-1;
          for (int t=0;t<ksel;t++){
            if (bd[t] > rmd || (bd[t]==rmd && bi[t]>rmi)){ rmd=bd[t]; rmi=bi[t]; rt=t; }
          }
          bd[rt]=d2; bi[rt]=jj;
          cmd=-FLT_MAX; cmi=-1;
          for (int t=0;t<ksel;t++){
            if (bd[t] > cmd || (bd[t]==cmd && bi[t]>cmi)){ cmd=bd[t]; cmi=bi[t]; }
          }
        }
      }
      for (int t=0;t<ksel;t++){
        int rt=-1; float mnd=FLT_MAX; int mni=INT_MAX;
        for (int u2=0;u2<ksel;u2++){
          if (bd[u2] < mnd || (bd[u2]==mnd && bi[u2]<mni)){ mnd=bd[u2]; mni=bi[u2]; rt=u2; }
        }
        bd[rt]=FLT_MAX; bi[rt]=INT_MAX;
        if (t >= ooff){
          float4 cp = candP[mni];
          float dist;
          {
#pragma clang fp contract(off)
            float dx=qv.x-cp.x, dy=qv.y-cp.y, dz=qv.z-cp.z;
            dist = (dx*dx + dy*dy) + dz*dz;
          }
          oidx[(size_t)qgq*KOUT + (t-ooff)]  = mni;
          odist[(size_t)qgq*KOUT + (t-ooff)] = dist;
        }
      }
    }
  }
}

// One message-passing block: out = self + lrelu(groupnorm(sum_k MLP(feat_k)))
// 4 threads per point: each handles 4 of the 16 neighbors, shfl-reduce.
template<bool SELF_ONES>
__global__ __launch_bounds__(256)
void mp_kernel(const float* __restrict__ self_feat,
               const float* __restrict__ nb_src,
               const int* __restrict__ idx,
               const float* __restrict__ dists,
               const float* __restrict__ w1g, const float* __restrict__ b1g,
               const float* __restrict__ w2g, const float* __restrict__ b2g,
               const float* __restrict__ gam, const float* __restrict__ bet,
               float* __restrict__ out, int n){
  __shared__ float w1[H*H], b1v[H], w2[D*H], b2v[D], gm[D], bt[D];
  for (int t=threadIdx.x; t<H*H; t+=blockDim.x) w1[t]=w1g[t];
  if (threadIdx.x < H) b1v[threadIdx.x]=b1g[threadIdx.x];
  for (int t=threadIdx.x; t<D*H; t+=blockDim.x) w2[t]=w2g[t];
  if (threadIdx.x < D){
    b2v[threadIdx.x]=b2g[threadIdx.x];
    gm[threadIdx.x]=gam[threadIdx.x];
    bt[threadIdx.x]=bet[threadIdx.x];
  }
  __syncthreads();
  int tt = blockIdx.x*blockDim.x + threadIdx.x;
  int p = tt >> 2, sub = tt & 3;
  if (p >= n) return;

  float s[D];
  #pragma unroll
  for (int j=0;j<D;j++) s[j] = SELF_ONES ? 1.0f : self_feat[p*D+j];
  float msg[D] = {0,0,0,0,0,0};

  #pragma unroll
  for (int u=0;u<KOUT/4;u++){
    int k = u*4 + sub;
    int j = idx[p*KOUT+k];
    float dd = dists[p*KOUT+k];
    float f[H];
    #pragma unroll
    for (int c=0;c<D;c++) f[c]=s[c];
    #pragma unroll
    for (int c=0;c<D;c++) f[D+c]=nb_src[j*D+c];
    f[2*D]=dd;
    float h[H];
    #pragma unroll
    for (int o=0;o<H;o++){
      float acc=b1v[o];
      #pragma unroll
      for (int c=0;c<H;c++) acc += w1[o*H+c]*f[c];
      h[o]=lrelu(acc);
    }
    #pragma unroll
    for (int o=0;o<D;o++){
      float acc=b2v[o];
      #pragma unroll
      for (int c=0;c<H;c++) acc += w2[o*H+c]*h[c];
      msg[o]+=acc;
    }
  }

  #pragma unroll
  for (int c=0;c<D;c++){
    msg[c] += __shfl_xor(msg[c], 1);
    msg[c] += __shfl_xor(msg[c], 2);
  }

  if (sub == 0){
    float y[D];
    #pragma unroll
    for (int gi=0; gi<2; gi++){
      float m0=msg[gi*3+0], m1=msg[gi*3+1], m2=msg[gi*3+2];
      float mu = ((m0+m1)+m2) / 3.0f;
      float d0=m0-mu, d1=m1-mu, d2v=m2-mu;
      float var = ((d0*d0 + d1*d1) + d2v*d2v) / 3.0f;
      float inv = 1.0f / sqrtf(var + GEPS);
      y[gi*3+0] = d0*inv;
      y[gi*3+1] = d1*inv;
      y[gi*3+2] = d2v*inv;
    }
    #pragma unroll
    for (int c=0;c<D;c++){
      float vv = y[c]*gm[c] + bt[c];
      out[p*D+c] = s[c] + lrelu(vv);
    }
  }
}

extern "C" void kernel_launch(void* const* d_in, const int* in_sizes, int n_in,
                              void* d_out, int out_size, void* d_ws, size_t ws_size,
                              hipStream_t stream){
  const float* xyz       = (const float*)d_in[0];
  const float* atom_xyz  = (const float*)d_in[1];
  const float* atomtypes = (const float*)d_in[2];
  const float* tt_w1 = (const float*)d_in[5];
  const float* tt_b1 = (const float*)d_in[6];
  const float* tt_w2 = (const float*)d_in[7];
  const float* tt_b2 = (const float*)d_in[8];
  const float* aa_w1 = (const float*)d_in[9];
  const float* aa_b1 = (const float*)d_in[10];
  const float* aa_w2 = (const float*)d_in[11];
  const float* aa_b2 = (const float*)d_in[12];
  const float* aa_gamma = (const float*)d_in[13];
  const float* aa_beta  = (const float*)d_in[14];
  const float* em_w1 = (const float*)d_in[15];
  const float* em_b1 = (const float*)d_in[16];
  const float* em_w2 = (const float*)d_in[17];
  const float* em_b2 = (const float*)d_in[18];
  const float* em_gamma = (const float*)d_in[19];
  const float* em_beta  = (const float*)d_in[20];

  const int n_pts = in_sizes[0]/3;
  const int n_at  = in_sizes[1]/3;

  char* ws = (char*)d_ws;
  float4* candP = (float4*)ws; ws += (size_t)MPAD*sizeof(float4);
  float4* ptsP  = (float4*)ws; ws += (size_t)n_pts*sizeof(float4);
  float* fa   = (float*)ws; ws += (size_t)n_at*D*4;
  float* fb   = (float*)ws; ws += (size_t)n_at*D*4;
  int*   idxA = (int*)ws;   ws += (size_t)n_at*KOUT*4;
  float* distA= (float*)ws; ws += (size_t)n_at*KOUT*4;
  int*   idxP = (int*)ws;   ws += (size_t)n_pts*KOUT*4;
  float* distP= (float*)ws; ws += (size_t)n_pts*KOUT*4;
  float* ea   = (float*)ws; ws += (size_t)n_pts*D*4;
  float* eb   = (float*)ws; ws += (size_t)n_pts*D*4;
  float* outf = (float*)d_out;

  pack_kernel<<<(MPAD+255)/256,256,0,stream>>>(atom_xyz, candP, n_at, MPAD);
  pack_kernel<<<(n_pts+255)/256,256,0,stream>>>(xyz, ptsP, n_pts, n_pts);

  tt_kernel<<<(n_at+255)/256,256,0,stream>>>(atomtypes, tt_w1,tt_b1,tt_w2,tt_b2, fa, n_at);

  // ---- fused KNN: blocks [0,nbA) = atom-atom k=17 drop-self;
  //                 blocks [nbA,nbA+nbB) = point-atom k=16 ----
  const int nbA = (n_at  + QBLK - 1) / QBLK;
  const int nbB = (n_pts + QBLK - 1) / QBLK;
  knn9_kernel<<<nbA + nbB,256,0,stream>>>(
      candP, n_at, candP, n_at, nbA, ptsP, n_pts,
      idxA, distA, idxP, distP);

  mp_kernel<false><<<(n_at*4+255)/256,256,0,stream>>>(fa, fa, idxA, distA,
      aa_w1+0*H*H, aa_b1+0*H, aa_w2+0*D*H, aa_b2+0*D, aa_gamma+0*D, aa_beta+0*D, fb, n_at);
  mp_kernel<false><<<(n_at*4+255)/256,256,0,stream>>>(fb, fb, idxA, distA,
      aa_w1+1*H*H, aa_b1+1*H, aa_w2+1*D*H, aa_b2+1*D, aa_gamma+1*D, aa_beta+1*D, fa, n_at);
  mp_kernel<false><<<(n_at*4+255)/256,256,0,stream>>>(fa, fa, idxA, distA,
      aa_w1+2*H*H, aa_b1+2*H, aa_w2+2*D*H, aa_b2+2*D, aa_gamma+2*D, aa_beta+2*D, fb, n_at);
  // final atom features in fb

  mp_kernel<true ><<<(n_pts*4+255)/256,256,0,stream>>>(nullptr, fb, idxP, distP,
      em_w1+0*H*H, em_b1+0*H, em_w2+0*D*H, em_b2+0*D, em_gamma+0*D, em_beta+0*D, ea, n_pts);
  mp_kernel<false><<<(n_pts*4+255)/256,256,0,stream>>>(ea, fb, idxP, distP,
      em_w1+1*H*H, em_b1+1*H, em_w2+1*D*H, em_b2+1*D, em_gamma+1*D, em_beta+1*D, eb, n_pts);
  mp_kernel<false><<<(n_pts*4+255)/256,256,0,stream>>>(eb, fb, idxP, distP,
      em_w1+2*H*H, em_b1+2*H, em_w2+2*D*H, em_b2+2*D, em_gamma+2*D, em_beta+2*D, outf, n_pts);
}